// Round 8
// baseline (328.375 us; speedup 1.0000x reference)
//
#include <hip/hip_runtime.h>
#include <hip/hip_bf16.h>

typedef __bf16 bf16x8_t __attribute__((ext_vector_type(8)));
typedef float floatx4_t __attribute__((ext_vector_type(4)));

#define H 128
#define BATCH 256
#define SEQ 1024
#define NROWS_TOTAL (BATCH * SEQ)            // 262144 rows of x
#define STEP_ELEMS 33521664.0f               // 256*1023*128
#define GRID 2048
#define NRT 16384                            // 16-row tiles

// ws layout: [0, 32768)      : Dpack, bf16, MFMA-B-fragment order [kt][n][lane][j]
//            [32768, 32780)  : accum[0]=step_sum, accum[1]=l2_sum, accum[2]=done ctr (int)
//            [65536, 131072) : T = A*A, fp32 row-major
//
// Algebra: f(y)=y@C.T is linear, so RK4 collapses to y1 = y·(I + D),
// D = A + A^2/2 + A^3/6 + A^4/24, A = C^T (truncated expm). Main pass is one
// streaming GEMM P = y·D (bf16 MFMA correction; residual (y-x1) exact fp32),
// reading x once: 134 MB -> HBM floor ~20 us.
// v8: ZERO-LDS / ZERO-BARRIER main. R7 counters: v7's (512,6) spilled
// (VGPR=40) -> revert; and the v4-v6 LDS round-trip + 2-barrier convoy costs
// ~11-15 us/CU of serial LDS-unit time (6.9M bank-conflict cycles). Residual
// is elementwise -> waves never share data: wave owns 16 rows x 32 cols,
// A-frags straight from global (4 waves/block read identical rows -> L1
// merge), B = 8 frags (32 VGPR), epilogue 10 scalar L1 hits. ~105 VGPR under
// the (256,4) cap -> 4 waves/SIMD, fill-like independent streaming.

// ---- prep stage 1: T = A*A (A = C^T), plus l2 term and accumulator init ----
__global__ __launch_bounds__(256) void prep_p1(const float* __restrict__ C,
                                               float* __restrict__ T,
                                               float* __restrict__ accum) {
  int e = blockIdx.x * 256 + threadIdx.x;    // 64 WGs * 256 = 16384 elements
  int i = e >> 7, j = e & 127;
  const float* Ci = C + i;                   // C[k][i], stride H — wave-broadcast
  const float* Cj = C + j * H;               // own row, stride 1
  float s = 0.f;
  #pragma unroll 8
  for (int k = 0; k < H; k++) s += Ci[k * H] * Cj[k];
  T[e] = s;

  if (blockIdx.x == 0) {
    float l2 = 0.f;
    for (int q = threadIdx.x; q < H * H; q += 256) {
      float c = C[q], c2 = c * c;
      l2 += c2 * c2;                         // sum C^4
    }
    #pragma unroll
    for (int off = 32; off > 0; off >>= 1) l2 += __shfl_down(l2, off);
    __shared__ float red[4];
    if ((threadIdx.x & 63) == 0) red[threadIdx.x >> 6] = l2;
    __syncthreads();
    if (threadIdx.x == 0) {
      accum[0] = 0.f;
      accum[1] = red[0] + red[1] + red[2] + red[3];
      *(int*)(accum + 2) = 0;                // re-zeroed every graph iteration
    }
  }
}

// ---- prep stage 2: D = A + T/2 + (T*A)/6 + (T*T)/24, packed to MFMA B-frag layout ----
__global__ __launch_bounds__(256) void prep_p2(const float* __restrict__ C,
                                               const float* __restrict__ T,
                                               __bf16* __restrict__ Dpack) {
  int e = blockIdx.x * 256 + threadIdx.x;
  int i = e >> 7, j = e & 127;
  const float* Ti = T + i * H;               // wave-broadcast row
  const float* Cj = C + j * H;               // own row
  const float* Tj = T + j;                   // column — L2-resident
  float s3 = 0.f, s4 = 0.f;
  #pragma unroll 8
  for (int k = 0; k < H; k++) {
    float t = Ti[k];
    s3 += t * Cj[k];
    s4 += t * Tj[k * H];
  }
  float d = C[j * H + i] + 0.5f * Ti[j] + s3 * (1.f / 6.f) + s4 * (1.f / 24.f);
  // pack: frag(kt,n), lane lanep, elem je holds D[kt*32 + (lanep>>4)*8 + je][n*16 + (lanep&15)]
  int kt = i >> 5, lq = (i >> 3) & 3, je = i & 7;
  int n = j >> 4, mm = j & 15;
  int lanep = lq * 16 + mm;
  Dpack[(size_t)(((kt * 8 + n) * 64 + lanep) * 8 + je)] = (__bf16)d;
}

// ---- main streaming pass: P = y*D via MFMA, residual + square + reduce + finalize ----
// 256 threads = 4 waves, NO LDS, NO barriers. All 4 waves of a block process
// the SAME 16-row tile (identical A-loads -> L1 merge); wave w owns output
// columns [32w, 32w+32).
__global__ __launch_bounds__(256, 4) void sindy_main(const float* __restrict__ x,
                                                     const __bf16* __restrict__ Dpack,
                                                     float* __restrict__ accum,
                                                     float* __restrict__ out) {
  int tid = threadIdx.x;
  int lane = tid & 63;
  int wave = tid >> 6;                       // n-quarter: cols [32*wave, +32)
  int m = lane & 15, quad = lane >> 4;

  // B fragments for this wave's 32-col strip: 8 frags = 32 VGPRs
  bf16x8_t breg[2][4];
  const bf16x8_t* Dp = (const bf16x8_t*)Dpack;
  #pragma unroll
  for (int n2 = 0; n2 < 2; n2++)
    #pragma unroll
    for (int kt = 0; kt < 4; kt++)
      breg[n2][kt] = Dp[(kt * 8 + wave * 2 + n2) * 64 + lane];

  float lsum = 0.f;

  for (int rt = blockIdx.x; rt < NRT; rt += GRID) {
    size_t row0 = (size_t)rt << 4;           // global row of this 16-row tile

    // ---- A-operand loads: lane (m,quad) reads x[row0+m][kt*32+quad*8 ..+8] ----
    const float* xa = x + ((row0 + m) << 7) + (quad << 3);
    floatx4_t u[8];
    #pragma unroll
    for (int kt = 0; kt < 4; kt++) {
      u[2 * kt]     = *(const floatx4_t*)(xa + kt * 32);
      u[2 * kt + 1] = *(const floatx4_t*)(xa + kt * 32 + 4);
    }

    // ---- epilogue sources (exact fp32, L1 hits on just-fetched rows):
    // rows row0 + quad*4 + t, col = wave*32 + n2*16 + m ----
    int srow = ((rt & 63) << 4) + (quad << 2);   // seq position of i2=0
    size_t gr = row0 + (quad << 2);
    float yv[2][5];
    #pragma unroll
    for (int n2 = 0; n2 < 2; n2++) {
      int c = (wave << 5) + (n2 << 4) + m;
      #pragma unroll
      for (int t = 0; t < 5; t++) {
        size_t r = gr + t;
        if (r > (size_t)(NROWS_TOTAL - 1)) r = (size_t)(NROWS_TOTAL - 1);
        yv[n2][t] = x[(r << 7) + c];
      }
    }

    // ---- pack A fragments (fp32 -> bf16) ----
    bf16x8_t af[4];
    #pragma unroll
    for (int kt = 0; kt < 4; kt++) {
      bf16x8_t a;
      a[0] = (__bf16)u[2 * kt][0]; a[1] = (__bf16)u[2 * kt][1];
      a[2] = (__bf16)u[2 * kt][2]; a[3] = (__bf16)u[2 * kt][3];
      a[4] = (__bf16)u[2 * kt + 1][0]; a[5] = (__bf16)u[2 * kt + 1][1];
      a[6] = (__bf16)u[2 * kt + 1][2]; a[7] = (__bf16)u[2 * kt + 1][3];
      af[kt] = a;
    }

    // ---- MFMA: P[16 rows][this wave's 32 cols] ----
    floatx4_t acc[2];
    acc[0] = (floatx4_t){0.f, 0.f, 0.f, 0.f};
    acc[1] = (floatx4_t){0.f, 0.f, 0.f, 0.f};
    #pragma unroll
    for (int kt = 0; kt < 4; kt++) {
      acc[0] = __builtin_amdgcn_mfma_f32_16x16x32_bf16(af[kt], breg[0][kt], acc[0], 0, 0, 0);
      acc[1] = __builtin_amdgcn_mfma_f32_16x16x32_bf16(af[kt], breg[1][kt], acc[1], 0, 0, 0);
    }

    // ---- residual: C/D row = quad*4 + i2, x1[s] = y[s+1] = yv[..][i2+1] ----
    #pragma unroll
    for (int n2 = 0; n2 < 2; n2++) {
      #pragma unroll
      for (int i2 = 0; i2 < 4; i2++) {
        if (srow + i2 <= SEQ - 2) {
          float rr = (yv[n2][i2] - yv[n2][i2 + 1]) + acc[n2][i2];
          lsum += rr * rr;
        }
      }
    }
  }

  #pragma unroll
  for (int off = 32; off > 0; off >>= 1) lsum += __shfl_down(lsum, off);
  __shared__ float red[4];
  if (lane == 0) red[wave] = lsum;
  __syncthreads();
  if (tid == 0) {
    atomicAdd(accum, red[0] + red[1] + red[2] + red[3]);
    // fused finalize: last block computes the scalar loss (counter zeroed by
    // prep_p1 every iteration; pattern validated in v7 run)
    __threadfence();
    int done = atomicAdd((int*)(accum + 2), 1);
    if (done == GRID - 1) {
      __threadfence();
      float a0 = atomicAdd(accum, 0.0f);     // device-scope load of final sum
      out[0] = a0 * (1.0f / STEP_ELEMS) + 0.001f * accum[1] * (1.0f / 16384.0f);
    }
  }
}

extern "C" void kernel_launch(void* const* d_in, const int* in_sizes, int n_in,
                              void* d_out, int out_size, void* d_ws, size_t ws_size,
                              hipStream_t stream) {
  const float* x = (const float*)d_in[0];
  const float* C = (const float*)d_in[1];
  __bf16* Dpack = (__bf16*)d_ws;
  float* accum = (float*)((char*)d_ws + 32768);
  float* T = (float*)((char*)d_ws + 65536);
  float* out = (float*)d_out;

  prep_p1<<<64, 256, 0, stream>>>(C, T, accum);
  prep_p2<<<64, 256, 0, stream>>>(C, T, Dpack);
  sindy_main<<<GRID, 256, 0, stream>>>(x, Dpack, accum, out);
}

// Round 9
// 261.232 us; speedup vs baseline: 1.2570x; 1.2570x over previous
//
#include <hip/hip_runtime.h>
#include <hip/hip_bf16.h>

typedef __bf16 bf16x8_t __attribute__((ext_vector_type(8)));
typedef float floatx4_t __attribute__((ext_vector_type(4)));

#define H 128
#define BATCH 256
#define SEQ 1024
#define NROWS_TOTAL (BATCH * SEQ)            // 262144 rows of x
#define STEP_ELEMS 33521664.0f               // 256*1023*128
#define GRID 1024

// ws layout: [0, 32768)      : Dpack, bf16, MFMA-B-fragment order [kt][n][lane][j]
//            [32768, 32780)  : accum[0]=step_sum, accum[1]=l2_sum, accum[2]=done ctr (int)
//            [65536, 131072) : T = A*A, fp32 row-major
//
// Algebra: f(y)=y@C.T is linear, so RK4 collapses to y1 = y·(I + D),
// D = A + A^2/2 + A^3/6 + A^4/24, A = C^T (truncated expm). Main pass is one
// streaming GEMM P = y·D (bf16 MFMA correction; residual (y-x1) exact fp32).
// v9 = v4 RESTORED byte-for-byte (best measured: 212.4 us; v5 pipeline, v6
// LDS-epilogue, v7 (512,6), v8 zero-LDS all null or worse — v7/v8 counters
// showed 40-VGPR codegen collapse -> serialized loads). Only delta vs v4:
// finalize fused into sindy_main's last block (validated in v7/v8 runs).

// ---- prep stage 1: T = A*A (A = C^T), plus l2 term and accumulator init ----
__global__ __launch_bounds__(256) void prep_p1(const float* __restrict__ C,
                                               float* __restrict__ T,
                                               float* __restrict__ accum) {
  int e = blockIdx.x * 256 + threadIdx.x;    // 64 WGs * 256 = 16384 elements
  int i = e >> 7, j = e & 127;
  const float* Ci = C + i;                   // C[k][i], stride H — wave-broadcast
  const float* Cj = C + j * H;               // own row, stride 1
  float s = 0.f;
  #pragma unroll 8
  for (int k = 0; k < H; k++) s += Ci[k * H] * Cj[k];
  T[e] = s;

  if (blockIdx.x == 0) {
    float l2 = 0.f;
    for (int q = threadIdx.x; q < H * H; q += 256) {
      float c = C[q], c2 = c * c;
      l2 += c2 * c2;                         // sum C^4
    }
    #pragma unroll
    for (int off = 32; off > 0; off >>= 1) l2 += __shfl_down(l2, off);
    __shared__ float red[4];
    if ((threadIdx.x & 63) == 0) red[threadIdx.x >> 6] = l2;
    __syncthreads();
    if (threadIdx.x == 0) {
      accum[0] = 0.f;
      accum[1] = red[0] + red[1] + red[2] + red[3];
      *(int*)(accum + 2) = 0;                // re-zeroed every graph iteration
    }
  }
}

// ---- prep stage 2: D = A + T/2 + (T*A)/6 + (T*T)/24, packed to MFMA B-frag layout ----
__global__ __launch_bounds__(256) void prep_p2(const float* __restrict__ C,
                                               const float* __restrict__ T,
                                               __bf16* __restrict__ Dpack) {
  int e = blockIdx.x * 256 + threadIdx.x;
  int i = e >> 7, j = e & 127;
  const float* Ti = T + i * H;               // wave-broadcast row
  const float* Cj = C + j * H;               // own row
  const float* Tj = T + j;                   // column — L2-resident
  float s3 = 0.f, s4 = 0.f;
  #pragma unroll 8
  for (int k = 0; k < H; k++) {
    float t = Ti[k];
    s3 += t * Cj[k];
    s4 += t * Tj[k * H];
  }
  float d = C[j * H + i] + 0.5f * Ti[j] + s3 * (1.f / 6.f) + s4 * (1.f / 24.f);
  // pack: frag(kt,n), lane lanep, elem je holds D[kt*32 + (lanep>>4)*8 + je][n*16 + (lanep&15)]
  int kt = i >> 5, lq = (i >> 3) & 3, je = i & 7;
  int n = j >> 4, mm = j & 15;
  int lanep = lq * 16 + mm;
  Dpack[(size_t)(((kt * 8 + n) * 64 + lanep) * 8 + je)] = (__bf16)d;
}

// ---- main streaming pass: P = y*D via MFMA, residual + square + reduce ----
// 512 threads = 8 waves; wave w owns output columns [16w, 16w+16).
__global__ __launch_bounds__(512, 4) void sindy_main(const float* __restrict__ x,
                                                     const __bf16* __restrict__ Dpack,
                                                     float* __restrict__ accum,
                                                     float* __restrict__ out) {
  // x-tile as bf16 MFMA-A fragments: [rowg][kt][lane][j], 16 KB, linear
  // per-lane frag addressing -> conflict-free b128 LDS traffic
  __shared__ __align__(16) __bf16 Atile[4][4][64][8];

  int tid = threadIdx.x;
  int lane = tid & 63;
  int wave = tid >> 6;                       // 0..7 = B n-frag index
  int m = lane & 15, quad = lane >> 4;
  int col = (wave << 4) + m;                 // output column of this lane

  // B fragments for this wave's 16-col strip: 4 frags = 16 VGPRs
  bf16x8_t breg[4];
  const bf16x8_t* Dp = (const bf16x8_t*)Dpack;
  #pragma unroll
  for (int kt = 0; kt < 4; kt++) breg[kt] = Dp[(kt * 8 + wave) * 64 + lane];

  // staging coords: thread loads row (tid>>3), 16-col group (tid&7)
  int srow_st = tid >> 3;                    // 0..63
  int g2 = tid & 7;
  int rowg_st = srow_st >> 4, m_st = srow_st & 15;
  int kt_st = g2 >> 1;
  int quad0 = (g2 & 1) << 1;                 // 0 or 2

  float lsum = 0.f;

  for (int tile = blockIdx.x; tile < 4096; tile += gridDim.x) {
    int b = tile >> 4;
    int ts = (tile & 15) << 6;               // s-base of 64-row tile
    int gb = b << 10;

    // ---- stage: 64x128 fp32 -> bf16 A-frags in LDS (each elem cvt'd once) ----
    {
      const float* src = x + (size_t)(gb + ts + srow_st) * H + (g2 << 4);
      floatx4_t u0 = *(const floatx4_t*)(src);
      floatx4_t u1 = *(const floatx4_t*)(src + 4);
      floatx4_t u2 = *(const floatx4_t*)(src + 8);
      floatx4_t u3 = *(const floatx4_t*)(src + 12);
      bf16x8_t f0, f1;
      f0[0] = (__bf16)u0[0]; f0[1] = (__bf16)u0[1]; f0[2] = (__bf16)u0[2]; f0[3] = (__bf16)u0[3];
      f0[4] = (__bf16)u1[0]; f0[5] = (__bf16)u1[1]; f0[6] = (__bf16)u1[2]; f0[7] = (__bf16)u1[3];
      f1[0] = (__bf16)u2[0]; f1[1] = (__bf16)u2[1]; f1[2] = (__bf16)u2[2]; f1[3] = (__bf16)u2[3];
      f1[4] = (__bf16)u3[0]; f1[5] = (__bf16)u3[1]; f1[6] = (__bf16)u3[2]; f1[7] = (__bf16)u3[3];
      *(bf16x8_t*)&Atile[rowg_st][kt_st][(quad0 + 0) * 16 + m_st][0] = f0;
      *(bf16x8_t*)&Atile[rowg_st][kt_st][(quad0 + 1) * 16 + m_st][0] = f1;
    }
    __syncthreads();

    // ---- MFMA: this wave computes P[all 64 rows][its 16 cols] ----
    floatx4_t acc[4];                        // [rowg]
    #pragma unroll
    for (int rg = 0; rg < 4; rg++) acc[rg] = (floatx4_t){0.f, 0.f, 0.f, 0.f};
    #pragma unroll
    for (int kt = 0; kt < 4; kt++) {
      bf16x8_t af[4];
      #pragma unroll
      for (int rg = 0; rg < 4; rg++) af[rg] = *(const bf16x8_t*)&Atile[rg][kt][lane][0];
      #pragma unroll
      for (int rg = 0; rg < 4; rg++)
        acc[rg] = __builtin_amdgcn_mfma_f32_16x16x32_bf16(af[rg], breg[kt], acc[rg], 0, 0, 0);
    }

    // ---- residual: exact fp32 from global (L1/L2 hits on just-fetched rows).
    // C/D layout: row = rowg*16 + quad*4 + i2, col = wave*16 + m.
    // x1[s] == y[s+1] -> 5 row-loads cover 4 residual rows.
    #pragma unroll
    for (int rg = 0; rg < 4; rg++) {
      int sr = ts + (rg << 4) + (quad << 2);
      const float* yp = x + (size_t)(gb + sr) * H + col;
      float yv[5];
      #pragma unroll
      for (int i2 = 0; i2 < 4; i2++) yv[i2] = yp[(size_t)i2 * H];
      size_t r4 = (size_t)(gb + sr) + 4;     // row sr+4: x1 of i2=3
      if (r4 > (size_t)(NROWS_TOTAL - 1)) r4 = (size_t)(NROWS_TOTAL - 1);
      yv[4] = x[r4 * H + col];
      #pragma unroll
      for (int i2 = 0; i2 < 4; i2++) {
        if (sr + i2 <= SEQ - 2) {
          float rr = (yv[i2] - yv[i2 + 1]) + acc[rg][i2];
          lsum += rr * rr;
        }
      }
    }
    __syncthreads();                         // protect Atile before next stage
  }

  #pragma unroll
  for (int off = 32; off > 0; off >>= 1) lsum += __shfl_down(lsum, off);
  __shared__ float red[8];
  if (lane == 0) red[wave] = lsum;
  __syncthreads();
  if (tid == 0) {
    float s = red[0] + red[1] + red[2] + red[3] + red[4] + red[5] + red[6] + red[7];
    atomicAdd(accum, s);
    // fused finalize: last block computes the scalar loss (counter zeroed by
    // prep_p1 every iteration; pattern correctness-validated in v7/v8 runs)
    __threadfence();
    int done = atomicAdd((int*)(accum + 2), 1);
    if (done == GRID - 1) {
      __threadfence();
      float a0 = atomicAdd(accum, 0.0f);     // device-scope load of final sum
      out[0] = a0 * (1.0f / STEP_ELEMS) + 0.001f * accum[1] * (1.0f / 16384.0f);
    }
  }
}

extern "C" void kernel_launch(void* const* d_in, const int* in_sizes, int n_in,
                              void* d_out, int out_size, void* d_ws, size_t ws_size,
                              hipStream_t stream) {
  const float* x = (const float*)d_in[0];
  const float* C = (const float*)d_in[1];
  __bf16* Dpack = (__bf16*)d_ws;
  float* accum = (float*)((char*)d_ws + 32768);
  float* T = (float*)((char*)d_ws + 65536);
  float* out = (float*)d_out;

  prep_p1<<<64, 256, 0, stream>>>(C, T, accum);
  prep_p2<<<64, 256, 0, stream>>>(C, T, Dpack);
  sindy_main<<<GRID, 512, 0, stream>>>(x, Dpack, accum, out);
}

// Round 10
// 214.858 us; speedup vs baseline: 1.5283x; 1.2158x over previous
//
#include <hip/hip_runtime.h>
#include <hip/hip_bf16.h>

typedef __bf16 bf16x8_t __attribute__((ext_vector_type(8)));
typedef float floatx4_t __attribute__((ext_vector_type(4)));

#define H 128
#define BATCH 256
#define SEQ 1024
#define NROWS_TOTAL (BATCH * SEQ)            // 262144 rows of x
#define STEP_ELEMS 33521664.0f               // 256*1023*128

// ws layout: [0, 32768)      : Dpack, bf16, MFMA-B-fragment order [kt][n][lane][j]
//            [32768, 32776)  : accum[0]=step_sum, accum[1]=l2_sum
//            [65536, 131072) : T = A*A, fp32 row-major
//
// Algebra: f(y)=y@C.T is linear, so RK4 collapses to y1 = y·(I + D),
// D = A + A^2/2 + A^3/6 + A^4/24, A = C^T (truncated expm). Main pass is one
// streaming GEMM P = y·D (bf16 MFMA correction; residual (y-x1) exact fp32).
// v10 = v4 RESTORED EXACTLY (best measured: 212.4 us). R9 isolated the fused
// last-block finalize as a ~2x main-kernel regression: the per-block
// __threadfence() (device-scope release -> cross-XCD L2 writeback) x1024
// blocks poisons L2 for the resident streaming blocks (main 53 -> 100 us,
// HBM 9%, all pipes idle). Separate 1-thread finalize_kernel restored.

// ---- prep stage 1: T = A*A (A = C^T), plus l2 term and accumulator init ----
__global__ __launch_bounds__(256) void prep_p1(const float* __restrict__ C,
                                               float* __restrict__ T,
                                               float* __restrict__ accum) {
  int e = blockIdx.x * 256 + threadIdx.x;    // 64 WGs * 256 = 16384 elements
  int i = e >> 7, j = e & 127;
  const float* Ci = C + i;                   // C[k][i], stride H — wave-broadcast
  const float* Cj = C + j * H;               // own row, stride 1
  float s = 0.f;
  #pragma unroll 8
  for (int k = 0; k < H; k++) s += Ci[k * H] * Cj[k];
  T[e] = s;

  if (blockIdx.x == 0) {
    float l2 = 0.f;
    for (int q = threadIdx.x; q < H * H; q += 256) {
      float c = C[q], c2 = c * c;
      l2 += c2 * c2;                         // sum C^4
    }
    #pragma unroll
    for (int off = 32; off > 0; off >>= 1) l2 += __shfl_down(l2, off);
    __shared__ float red[4];
    if ((threadIdx.x & 63) == 0) red[threadIdx.x >> 6] = l2;
    __syncthreads();
    if (threadIdx.x == 0) {
      accum[0] = 0.f;
      accum[1] = red[0] + red[1] + red[2] + red[3];
    }
  }
}

// ---- prep stage 2: D = A + T/2 + (T*A)/6 + (T*T)/24, packed to MFMA B-frag layout ----
__global__ __launch_bounds__(256) void prep_p2(const float* __restrict__ C,
                                               const float* __restrict__ T,
                                               __bf16* __restrict__ Dpack) {
  int e = blockIdx.x * 256 + threadIdx.x;
  int i = e >> 7, j = e & 127;
  const float* Ti = T + i * H;               // wave-broadcast row
  const float* Cj = C + j * H;               // own row
  const float* Tj = T + j;                   // column — L2-resident
  float s3 = 0.f, s4 = 0.f;
  #pragma unroll 8
  for (int k = 0; k < H; k++) {
    float t = Ti[k];
    s3 += t * Cj[k];
    s4 += t * Tj[k * H];
  }
  float d = C[j * H + i] + 0.5f * Ti[j] + s3 * (1.f / 6.f) + s4 * (1.f / 24.f);
  // pack: frag(kt,n), lane lanep, elem je holds D[kt*32 + (lanep>>4)*8 + je][n*16 + (lanep&15)]
  int kt = i >> 5, lq = (i >> 3) & 3, je = i & 7;
  int n = j >> 4, mm = j & 15;
  int lanep = lq * 16 + mm;
  Dpack[(size_t)(((kt * 8 + n) * 64 + lanep) * 8 + je)] = (__bf16)d;
}

// ---- main streaming pass: P = y*D via MFMA, residual + square + reduce ----
// 512 threads = 8 waves; wave w owns output columns [16w, 16w+16).
__global__ __launch_bounds__(512, 4) void sindy_main(const float* __restrict__ x,
                                                     const __bf16* __restrict__ Dpack,
                                                     float* __restrict__ accum) {
  // x-tile as bf16 MFMA-A fragments: [rowg][kt][lane][j], 16 KB, linear
  // per-lane frag addressing -> conflict-free b128 LDS traffic
  __shared__ __align__(16) __bf16 Atile[4][4][64][8];

  int tid = threadIdx.x;
  int lane = tid & 63;
  int wave = tid >> 6;                       // 0..7 = B n-frag index
  int m = lane & 15, quad = lane >> 4;
  int col = (wave << 4) + m;                 // output column of this lane

  // B fragments for this wave's 16-col strip: 4 frags = 16 VGPRs
  bf16x8_t breg[4];
  const bf16x8_t* Dp = (const bf16x8_t*)Dpack;
  #pragma unroll
  for (int kt = 0; kt < 4; kt++) breg[kt] = Dp[(kt * 8 + wave) * 64 + lane];

  // staging coords: thread loads row (tid>>3), 16-col group (tid&7)
  int srow_st = tid >> 3;                    // 0..63
  int g2 = tid & 7;
  int rowg_st = srow_st >> 4, m_st = srow_st & 15;
  int kt_st = g2 >> 1;
  int quad0 = (g2 & 1) << 1;                 // 0 or 2

  float lsum = 0.f;

  for (int tile = blockIdx.x; tile < 4096; tile += gridDim.x) {
    int b = tile >> 4;
    int ts = (tile & 15) << 6;               // s-base of 64-row tile
    int gb = b << 10;

    // ---- stage: 64x128 fp32 -> bf16 A-frags in LDS (each elem cvt'd once) ----
    {
      const float* src = x + (size_t)(gb + ts + srow_st) * H + (g2 << 4);
      floatx4_t u0 = *(const floatx4_t*)(src);
      floatx4_t u1 = *(const floatx4_t*)(src + 4);
      floatx4_t u2 = *(const floatx4_t*)(src + 8);
      floatx4_t u3 = *(const floatx4_t*)(src + 12);
      bf16x8_t f0, f1;
      f0[0] = (__bf16)u0[0]; f0[1] = (__bf16)u0[1]; f0[2] = (__bf16)u0[2]; f0[3] = (__bf16)u0[3];
      f0[4] = (__bf16)u1[0]; f0[5] = (__bf16)u1[1]; f0[6] = (__bf16)u1[2]; f0[7] = (__bf16)u1[3];
      f1[0] = (__bf16)u2[0]; f1[1] = (__bf16)u2[1]; f1[2] = (__bf16)u2[2]; f1[3] = (__bf16)u2[3];
      f1[4] = (__bf16)u3[0]; f1[5] = (__bf16)u3[1]; f1[6] = (__bf16)u3[2]; f1[7] = (__bf16)u3[3];
      *(bf16x8_t*)&Atile[rowg_st][kt_st][(quad0 + 0) * 16 + m_st][0] = f0;
      *(bf16x8_t*)&Atile[rowg_st][kt_st][(quad0 + 1) * 16 + m_st][0] = f1;
    }
    __syncthreads();

    // ---- MFMA: this wave computes P[all 64 rows][its 16 cols] ----
    floatx4_t acc[4];                        // [rowg]
    #pragma unroll
    for (int rg = 0; rg < 4; rg++) acc[rg] = (floatx4_t){0.f, 0.f, 0.f, 0.f};
    #pragma unroll
    for (int kt = 0; kt < 4; kt++) {
      bf16x8_t af[4];
      #pragma unroll
      for (int rg = 0; rg < 4; rg++) af[rg] = *(const bf16x8_t*)&Atile[rg][kt][lane][0];
      #pragma unroll
      for (int rg = 0; rg < 4; rg++)
        acc[rg] = __builtin_amdgcn_mfma_f32_16x16x32_bf16(af[rg], breg[kt], acc[rg], 0, 0, 0);
    }

    // ---- residual: exact fp32 from global (L1/L2 hits on just-fetched rows).
    // C/D layout: row = rowg*16 + quad*4 + i2, col = wave*16 + m.
    // x1[s] == y[s+1] -> 5 row-loads cover 4 residual rows.
    #pragma unroll
    for (int rg = 0; rg < 4; rg++) {
      int sr = ts + (rg << 4) + (quad << 2);
      const float* yp = x + (size_t)(gb + sr) * H + col;
      float yv[5];
      #pragma unroll
      for (int i2 = 0; i2 < 4; i2++) yv[i2] = yp[(size_t)i2 * H];
      size_t r4 = (size_t)(gb + sr) + 4;     // row sr+4: x1 of i2=3
      if (r4 > (size_t)(NROWS_TOTAL - 1)) r4 = (size_t)(NROWS_TOTAL - 1);
      yv[4] = x[r4 * H + col];
      #pragma unroll
      for (int i2 = 0; i2 < 4; i2++) {
        if (sr + i2 <= SEQ - 2) {
          float rr = (yv[i2] - yv[i2 + 1]) + acc[rg][i2];
          lsum += rr * rr;
        }
      }
    }
    __syncthreads();                         // protect Atile before next stage
  }

  #pragma unroll
  for (int off = 32; off > 0; off >>= 1) lsum += __shfl_down(lsum, off);
  __shared__ float red[8];
  if (lane == 0) red[wave] = lsum;
  __syncthreads();
  if (tid == 0) {
    float s = red[0] + red[1] + red[2] + red[3] + red[4] + red[5] + red[6] + red[7];
    atomicAdd(accum, s);
  }
}

__global__ void finalize_kernel(const float* __restrict__ accum, float* __restrict__ out) {
  out[0] = accum[0] * (1.0f / STEP_ELEMS) + 0.001f * accum[1] * (1.0f / 16384.0f);
}

extern "C" void kernel_launch(void* const* d_in, const int* in_sizes, int n_in,
                              void* d_out, int out_size, void* d_ws, size_t ws_size,
                              hipStream_t stream) {
  const float* x = (const float*)d_in[0];
  const float* C = (const float*)d_in[1];
  __bf16* Dpack = (__bf16*)d_ws;
  float* accum = (float*)((char*)d_ws + 32768);
  float* T = (float*)((char*)d_ws + 65536);
  float* out = (float*)d_out;

  prep_p1<<<64, 256, 0, stream>>>(C, T, accum);
  prep_p2<<<64, 256, 0, stream>>>(C, T, Dpack);
  sindy_main<<<1024, 512, 0, stream>>>(x, Dpack, accum);
  finalize_kernel<<<1, 1, 0, stream>>>(accum, out);
}